// Round 2
// baseline (549.256 us; speedup 1.0000x reference)
//
#include <hip/hip_runtime.h>
#include <math.h>

typedef __attribute__((ext_vector_type(8))) short bf16x8;
typedef __attribute__((ext_vector_type(4))) float f32x4;
typedef __attribute__((ext_vector_type(4))) unsigned short u16x4;

__device__ inline unsigned short f2bf(float f) {
    union { float f; unsigned u; } v; v.f = f;
    unsigned r = v.u + 0x7FFFu + ((v.u >> 16) & 1u);   // RNE
    return (unsigned short)(r >> 16);
}
__device__ inline float bf2f(unsigned short h) {
    union { unsigned u; float f; } v; v.u = ((unsigned)h) << 16;
    return v.f;
}

// async 16B global -> LDS. LDS dest is wave-uniform base + lane*16 (m104).
__device__ inline void load_lds16(const void* g, void* l) {
    __builtin_amdgcn_global_load_lds(
        (const __attribute__((address_space(1))) unsigned int*)g,
        (__attribute__((address_space(3))) unsigned int*)l,
        16, 0, 0);
}

// One-launch f32->bf16 convert of 4 segments (seg 3 zero-padded nDs..nDd).
__global__ __launch_bounds__(256) void convert_all(
    const float* __restrict__ sA, unsigned short* __restrict__ dA, long nA,
    const float* __restrict__ sB, unsigned short* __restrict__ dB, long nB,
    const float* __restrict__ sC, unsigned short* __restrict__ dC, long nC,
    const float* __restrict__ sD, unsigned short* __restrict__ dD, long nDs, long nDd)
{
    long i = ((long)blockIdx.x * 256 + threadIdx.x) * 4;
    const float* s; unsigned short* d; long nsrc;
    if (i < nA)              { s = sA + i; d = dA + i; nsrc = nA - i; }
    else if ((i -= nA) < nB) { s = sB + i; d = dB + i; nsrc = nB - i; }
    else if ((i -= nB) < nC) { s = sC + i; d = dC + i; nsrc = nC - i; }
    else if ((i -= nC) < nDd){ s = sD + i; d = dD + i; nsrc = nDs - i; }
    else return;
    float4 v = make_float4(0.f, 0.f, 0.f, 0.f);
    if (nsrc >= 4) v = *(const float4*)s;
    u16x4 o;
    o[0] = f2bf(v.x); o[1] = f2bf(v.y); o[2] = f2bf(v.z); o[3] = f2bf(v.w);
    *(u16x4*)d = o;
}

// ---------------------------------------------------------------------------
// Old 128x128 kernel (m97 structure) — retained for gemm1 (MODE 3 only used).
// ---------------------------------------------------------------------------
template <int MODE, bool SWZ>
__global__ __launch_bounds__(256) void gemm_bf16(
    const unsigned short* __restrict__ A, const unsigned short* __restrict__ Bm,
    const float* __restrict__ bias0, const float* __restrict__ bias1,
    void* __restrict__ out0v, void* __restrict__ out1v,
    int M, int Npad, int Nreal, int K, int nsplit)
{
    __shared__ __align__(16) unsigned short As[128 * 64];
    __shared__ __align__(16) unsigned short Bs[128 * 64];

    const int tid  = threadIdx.x;
    const int nblk = Npad >> 7;
    int mt, nt;
    if constexpr (SWZ) {
        const int per = (M >> 7) >> 3;
        const int x = blockIdx.x & 7;
        const int j = blockIdx.x >> 3;
        const int jm = j / nblk;
        mt = x * per + jm;
        nt = j - jm * nblk;
    } else {
        mt = blockIdx.x / nblk;
        nt = blockIdx.x - mt * nblk;
    }
    const int m0 = mt << 7;
    const int n0 = nt << 7;

    const int lane = tid & 63;
    const int wid  = tid >> 6;
    const int wm   = (wid & 1) << 6;
    const int wn   = (wid >> 1) << 6;
    const int quad = lane >> 4;
    const int l15  = lane & 15;
    const int l7   = l15 & 7;

    const int lrow = lane >> 3;
    const int lcol = ((lane & 7) ^ lrow) << 3;

    const unsigned short* Ab = A  + (size_t)(m0 + wid * 32 + lrow) * K + lcol;
    const unsigned short* Bb = Bm + (size_t)(n0 + wid * 32 + lrow) * K + lcol;
    unsigned short* AsW = &As[(wid * 32) * 64];
    unsigned short* BsW = &Bs[(wid * 32) * 64];

    f32x4 acc[4][4];
    #pragma unroll
    for (int i = 0; i < 4; ++i)
        #pragma unroll
        for (int j = 0; j < 4; ++j)
            acc[i][j] = f32x4{0.f, 0.f, 0.f, 0.f};

    for (int kt = 0; kt < K; kt += 64) {
        __syncthreads();
        #pragma unroll
        for (int i = 0; i < 4; ++i) {
            load_lds16(Ab + (size_t)(i * 8) * K + kt, AsW + i * 8 * 64);
            load_lds16(Bb + (size_t)(i * 8) * K + kt, BsW + i * 8 * 64);
        }
        __syncthreads();

        #pragma unroll
        for (int kk = 0; kk < 64; kk += 32) {
            const int kq = kk >> 3;
            bf16x8 af[4], bfv[4];
            #pragma unroll
            for (int mi = 0; mi < 4; ++mi)
                af[mi] = *(const bf16x8*)&As[(wm + mi * 16 + l15) * 64
                                             + (((kq + quad) ^ l7) << 3)];
            #pragma unroll
            for (int ni = 0; ni < 4; ++ni)
                bfv[ni] = *(const bf16x8*)&Bs[(wn + ni * 16 + l15) * 64
                                              + (((kq + quad) ^ l7) << 3)];
            #pragma unroll
            for (int mi = 0; mi < 4; ++mi)
                #pragma unroll
                for (int ni = 0; ni < 4; ++ni)
                    acc[mi][ni] = __builtin_amdgcn_mfma_f32_16x16x32_bf16(
                        bfv[ni], af[mi], acc[mi][ni], 0, 0, 0);
        }
    }

    if constexpr (MODE == 2) {
        float* o = (float*)out0v;
        #pragma unroll
        for (int ni = 0; ni < 4; ++ni) {
            const int nb = n0 + wn + ni * 16 + (quad << 2);
            if (nb >= Nreal) continue;
            const float4 bv = *(const float4*)&bias0[nb];
            #pragma unroll
            for (int mi = 0; mi < 4; ++mi) {
                const int m = m0 + wm + mi * 16 + l15;
                f32x4 v;
                v[0] = (acc[mi][ni][0] + bv.x) * (1.0f / 1.5f);
                v[1] = (acc[mi][ni][1] + bv.y) * (1.0f / 1.5f);
                v[2] = (acc[mi][ni][2] + bv.z) * (1.0f / 1.5f);
                v[3] = (acc[mi][ni][3] + bv.w) * (1.0f / 1.5f);
                *(f32x4*)&o[(size_t)m * Nreal + nb] = v;
            }
        }
    } else {  // MODE 3
        if (n0 < nsplit) {
            unsigned short* o = (unsigned short*)out0v;
            #pragma unroll
            for (int ni = 0; ni < 4; ++ni) {
                const int nb = n0 + wn + ni * 16 + (quad << 2);
                const float4 bv = *(const float4*)&bias0[nb];
                #pragma unroll
                for (int mi = 0; mi < 4; ++mi) {
                    const int m = m0 + wm + mi * 16 + l15;
                    u16x4 ov;
                    ov[0] = f2bf(acc[mi][ni][0] + bv.x);
                    ov[1] = f2bf(acc[mi][ni][1] + bv.y);
                    ov[2] = f2bf(acc[mi][ni][2] + bv.z);
                    ov[3] = f2bf(acc[mi][ni][3] + bv.w);
                    *(u16x4*)&o[(size_t)m * nsplit + nb] = ov;
                }
            }
        } else {
            float* o = (float*)out1v;
            const int ld1 = Npad - nsplit;
            #pragma unroll
            for (int ni = 0; ni < 4; ++ni) {
                const int nb = n0 + wn + ni * 16 + (quad << 2) - nsplit;
                const float4 bv = *(const float4*)&bias1[nb];
                #pragma unroll
                for (int mi = 0; mi < 4; ++mi) {
                    const int m = m0 + wm + mi * 16 + l15;
                    f32x4 v;
                    #pragma unroll
                    for (int r = 0; r < 4; ++r) {
                        float x = acc[mi][ni][r] + ((const float*)&bv)[r];
                        float sp = (x > 20.f) ? x : log1pf(expf(x));
                        v[r] = sp + 1e-3f;
                    }
                    *(f32x4*)&o[(size_t)m * ld1 + nb] = v;
                }
            }
        }
    }
}

// ---------------------------------------------------------------------------
// NEW: 256x256 / 512-thread / 8-phase pipelined GEMM for the logits GEMM.
// out[m,n] = (sum_k A[m,k]*B[n,k] + bias[n]) / 1.5, f32, nontemporal stores.
// 8 waves (2M x 4N): wave = 128x64 output = acc[8][4] 16x16 fragments.
// Per K-tile (BK=64): 4 phases in gray order (qm,kh): (0,0)(1,0)(1,1)(0,1);
// each phase reads only the fragments it newly needs (A:4, B:4 or 0) ->
// 24 ds_read_b128 / K-tile / wave (HK density), then 16 MFMA between raw
// barriers with setprio(1) (T5). Iteration = 2 K-tiles (buf0=even, buf1=odd).
// Stage schedule (global_load_lds, chunk-XOR pre-swizzled source):
//   buf1 (tile 2I+1) staged at P1/P2 (buf1 freed at prev P8 barrier),
//   buf0 (tile 2I+2) staged at P5/P6 (buf0 freed at P4 barrier).
// vmcnt(0) only at the two half-iteration boundaries (stages lead the drain
// by 2-4 phases; no mid-phase drains) — per-wave waitcnt BEFORE the barrier
// publishes completion to reader waves. asm s_barrier with "memory" clobber
// fences all memory ops into their phase window at compiler level.
// LDS 128 KiB -> 1 block/CU, 2 waves/SIMD (HK operating point).
template <bool SWZ>
__global__ __launch_bounds__(512, 2) void gemm2_256(
    const unsigned short* __restrict__ A, const unsigned short* __restrict__ Bm,
    const float* __restrict__ bias0, float* __restrict__ out,
    int M, int Npad, int Nreal, int K)
{
    __shared__ __align__(16) unsigned short As[2 * 256 * 64];
    __shared__ __align__(16) unsigned short Bs[2 * 256 * 64];

    const int nblk = Npad >> 8;
    int mt, nt;
    if constexpr (SWZ) {
        const int per = (M >> 8) >> 3;
        const int x = blockIdx.x & 7;
        const int j = blockIdx.x >> 3;
        const int jm = j / nblk;
        mt = x * per + jm;
        nt = j - jm * nblk;
    } else {
        mt = blockIdx.x / nblk;
        nt = blockIdx.x - mt * nblk;
    }
    const int m0 = mt << 8;
    const int n0 = nt << 8;

    const int tid  = threadIdx.x;
    const int lane = tid & 63;
    const int wid  = tid >> 6;       // 0..7
    const int wmh  = wid >> 2;       // 0..1 : A half (rows wmh*128..)
    const int wnq  = wid & 3;        // 0..3 : B quarter (cols wnq*64..)
    const int quad = lane >> 4;
    const int l15  = lane & 15;
    const int l7   = l15 & 7;
    const int lrow = lane >> 3;
    const int lcol = ((lane & 7) ^ lrow) << 3;   // pre-swizzled global chunk

    // staging: wave w owns rows [w*32, w*32+32) of BOTH tiles; 4 chunks of
    // 8 rows each per operand per K-tile (1 KiB per gload_lds issue).
    const unsigned short* Ab = A  + (size_t)(m0 + wid * 32 + lrow) * K + lcol;
    const unsigned short* Bb = Bm + (size_t)(n0 + wid * 32 + lrow) * K + lcol;
    unsigned short* AsW = &As[(wid * 32) * 64];
    unsigned short* BsW = &Bs[(wid * 32) * 64];

#define STG_A(bi, kt) { \
    const unsigned short* g_ = Ab + (size_t)(kt); \
    unsigned short* l_ = AsW + (bi) * 16384; \
    load_lds16(g_, l_); \
    load_lds16(g_ + 8 * (size_t)K,  l_ + 512); \
    load_lds16(g_ + 16 * (size_t)K, l_ + 1024); \
    load_lds16(g_ + 24 * (size_t)K, l_ + 1536); }
#define STG_B(bi, kt) { \
    const unsigned short* g_ = Bb + (size_t)(kt); \
    unsigned short* l_ = BsW + (bi) * 16384; \
    load_lds16(g_, l_); \
    load_lds16(g_ + 8 * (size_t)K,  l_ + 512); \
    load_lds16(g_ + 16 * (size_t)K, l_ + 1024); \
    load_lds16(g_ + 24 * (size_t)K, l_ + 1536); }
#define RD_A(bi, qm, kh) { \
    const unsigned short* p_ = &As[(bi) * 16384]; \
    _Pragma("unroll") \
    for (int i_ = 0; i_ < 4; ++i_) { \
        const int row_ = wmh * 128 + ((qm) * 4 + i_) * 16 + l15; \
        af[i_] = *(const bf16x8*)&p_[row_ * 64 + ((((kh) * 4 + quad) ^ l7) << 3)]; } }
#define RD_B(bi, kh) { \
    const unsigned short* p_ = &Bs[(bi) * 16384]; \
    _Pragma("unroll") \
    for (int i_ = 0; i_ < 4; ++i_) { \
        const int row_ = wnq * 64 + i_ * 16 + l15; \
        bfv[i_] = *(const bf16x8*)&p_[row_ * 64 + ((((kh) * 4 + quad) ^ l7) << 3)]; } }
#define MM(qm) { \
    __builtin_amdgcn_s_setprio(1); \
    _Pragma("unroll") \
    for (int i_ = 0; i_ < 4; ++i_) \
        _Pragma("unroll") \
        for (int j_ = 0; j_ < 4; ++j_) \
            acc[(qm) * 4 + i_][j_] = __builtin_amdgcn_mfma_f32_16x16x32_bf16( \
                bfv[j_], af[i_], acc[(qm) * 4 + i_][j_], 0, 0, 0); \
    __builtin_amdgcn_s_setprio(0); }
#define BAR()   asm volatile("s_barrier" ::: "memory")
#define WLGKM() asm volatile("s_waitcnt lgkmcnt(0)" ::: "memory")
#define WVM0()  asm volatile("s_waitcnt vmcnt(0)" ::: "memory")
#define WVM8()  asm volatile("s_waitcnt vmcnt(8)" ::: "memory")

    f32x4 acc[8][4];
    #pragma unroll
    for (int i = 0; i < 8; ++i)
        #pragma unroll
        for (int j = 0; j < 4; ++j)
            acc[i][j] = f32x4{0.f, 0.f, 0.f, 0.f};

    bf16x8 af[4], bfv[4];

    // prologue: tile0 -> buf0, tile1 -> buf1; wait tile0 (allow tile1 in flight)
    STG_A(0, 0); STG_B(0, 0);
    STG_A(1, 64); STG_B(1, 64);
    WVM8();
    BAR();

    const int NI = K >> 7;   // iterations over pairs of K-tiles
    for (int I = 0; I < NI; ++I) {
        const int keven = I << 7;            // k-offset of tile 2I
        // ---- phases 1-4: tile 2I from buf0; stage tile 2I+1 -> buf1 ----
        RD_A(0, 0, 0); RD_B(0, 0);
        if (I > 0) STG_A(1, keven + 64);
        BAR(); WLGKM(); MM(0);
        BAR();
        RD_A(0, 1, 0);
        if (I > 0) STG_B(1, keven + 64);
        BAR(); WLGKM(); MM(1);
        BAR();
        RD_A(0, 1, 1); RD_B(0, 1);
        BAR(); WLGKM(); MM(1);
        BAR();
        RD_A(0, 0, 1);
        BAR(); WLGKM(); MM(0);
        WVM0();                               // tile 2I+1 fully landed
        BAR();
        // ---- phases 5-8: tile 2I+1 from buf1; stage tile 2I+2 -> buf0 ----
        RD_A(1, 0, 0); RD_B(1, 0);
        if (I + 1 < NI) STG_A(0, keven + 128);
        BAR(); WLGKM(); MM(0);
        BAR();
        RD_A(1, 1, 0);
        if (I + 1 < NI) STG_B(0, keven + 128);
        BAR(); WLGKM(); MM(1);
        BAR();
        RD_A(1, 1, 1); RD_B(1, 1);
        BAR(); WLGKM(); MM(1);
        BAR();
        RD_A(1, 0, 1);
        BAR(); WLGKM(); MM(0);
        WVM0();                               // tile 2I+2 fully landed
        BAR();
    }

    // epilogue (swapped-operand layout): m = ...+l15, n = ...+quad*4+reg
    #pragma unroll
    for (int ni = 0; ni < 4; ++ni) {
        const int nb = n0 + wnq * 64 + ni * 16 + (quad << 2);
        if (nb < Nreal) {                     // Nreal%4==0: all-or-nothing
            const float4 bv = *(const float4*)&bias0[nb];
            #pragma unroll
            for (int mi = 0; mi < 8; ++mi) {
                const int m = m0 + wmh * 128 + mi * 16 + l15;
                f32x4 v;
                v[0] = (acc[mi][ni][0] + bv.x) * (1.0f / 1.5f);
                v[1] = (acc[mi][ni][1] + bv.y) * (1.0f / 1.5f);
                v[2] = (acc[mi][ni][2] + bv.z) * (1.0f / 1.5f);
                v[3] = (acc[mi][ni][3] + bv.w) * (1.0f / 1.5f);
                __builtin_nontemporal_store(v, (f32x4*)&out[(size_t)m * Nreal + nb]);
            }
        }
    }
#undef STG_A
#undef STG_B
#undef RD_A
#undef RD_B
#undef MM
#undef BAR
#undef WLGKM
#undef WVM0
#undef WVM8
}

// pre[b,s,d] = f[b,d] + sum_r L[b,d,r]*z[b,s,r] + diag[b,d]*nd[b,s,d], bf16.
__global__ __launch_bounds__(256) void sample_kernel(
    const float* __restrict__ features, const unsigned short* __restrict__ lr_cov,
    const float* __restrict__ diag, const float* __restrict__ nz_lr,
    const float* __restrict__ nz_diag, unsigned short* __restrict__ pre,
    int S, int D)
{
    const int tid = threadIdx.x;
    const int b   = blockIdx.x;
    const int sh  = tid >> 7;
    const int t   = tid & 127;
    const int d0  = t << 2;

    __shared__ __align__(16) float snz[64 * 16];
    ((float4*)snz)[tid] = ((const float4*)(nz_lr + (size_t)b * S * 16))[tid];

    float4 f  = *(const float4*)(features + (size_t)b * D + d0);
    float4 dg = *(const float4*)(diag + (size_t)b * D + d0);
    float L[4][16];
    const unsigned short* lp = lr_cov + (size_t)b * D * 16 + (size_t)d0 * 16;
    #pragma unroll
    for (int j = 0; j < 4; ++j) {
        bf16x8 a = *(const bf16x8*)(lp + j * 16);
        bf16x8 c = *(const bf16x8*)(lp + j * 16 + 8);
        #pragma unroll
        for (int r = 0; r < 8; ++r) {
            L[j][r]     = bf2f((unsigned short)a[r]);
            L[j][8 + r] = bf2f((unsigned short)c[r]);
        }
    }
    __syncthreads();

    const int s0 = sh * (S >> 1);
    const float* ndp = nz_diag + (size_t)b * S * D + (size_t)s0 * D + d0;
    unsigned short* pp = pre + (size_t)b * S * D + (size_t)s0 * D + d0;
    const int SH = S >> 1;
    for (int s = 0; s < SH; s += 2) {
        float4 nd0 = *(const float4*)(ndp + (size_t)s * D);
        float4 nd1 = *(const float4*)(ndp + (size_t)(s + 1) * D);
        float a0 = f.x + dg.x * nd0.x, a1 = f.y + dg.y * nd0.y;
        float a2 = f.z + dg.z * nd0.z, a3 = f.w + dg.w * nd0.w;
        float b0 = f.x + dg.x * nd1.x, b1 = f.y + dg.y * nd1.y;
        float b2 = f.z + dg.z * nd1.z, b3 = f.w + dg.w * nd1.w;
        const float* z0 = &snz[(s0 + s) * 16];
        const float* z1 = &snz[(s0 + s + 1) * 16];
        #pragma unroll
        for (int r = 0; r < 16; ++r) {
            float zv0 = z0[r], zv1 = z1[r];
            a0 += L[0][r] * zv0; a1 += L[1][r] * zv0;
            a2 += L[2][r] * zv0; a3 += L[3][r] * zv0;
            b0 += L[0][r] * zv1; b1 += L[1][r] * zv1;
            b2 += L[2][r] * zv1; b3 += L[3][r] * zv1;
        }
        u16x4 o0, o1;
        o0[0] = f2bf(a0); o0[1] = f2bf(a1); o0[2] = f2bf(a2); o0[3] = f2bf(a3);
        o1[0] = f2bf(b0); o1[1] = f2bf(b1); o1[2] = f2bf(b2); o1[3] = f2bf(b3);
        *(u16x4*)(pp + (size_t)s * D) = o0;
        *(u16x4*)(pp + (size_t)(s + 1) * D) = o1;
    }
}

extern "C" void kernel_launch(void* const* d_in, const int* in_sizes, int n_in,
                              void* d_out, int out_size, void* d_ws, size_t ws_size,
                              hipStream_t stream)
{
    const float* features = (const float*)d_in[0];
    const float* W_cov    = (const float*)d_in[1];
    const float* b_cov    = (const float*)d_in[2];
    const float* W_diag   = (const float*)d_in[3];
    const float* b_diag   = (const float*)d_in[4];
    const float* W_cls    = (const float*)d_in[5];
    const float* b_cls    = (const float*)d_in[6];
    const float* nz_diag  = (const float*)d_in[7];
    const float* nz_lr    = (const float*)d_in[8];

    const int D    = in_sizes[4];            // 512
    const int DR   = in_sizes[2];            // 8192
    const int B    = in_sizes[0] / D;        // 1024
    const int S    = in_sizes[7] / (B * D);  // 64
    const int C    = in_sizes[6];            // 1000
    const int M    = B * S;                  // 65536
    const int Cpad = (C + 255) & ~255;       // 1024 (multiple of 256 for gemm2_256)
    const int Ncat = DR + D;                 // 8704

    char* ws = (char*)d_ws;
    unsigned short* lrcov = (unsigned short*)ws;                      // B*DR bf16
    float*          diag  = (float*)(ws + (size_t)B * DR * 2);        // B*D f32
    unsigned short* wclsb = (unsigned short*)((char*)diag + (size_t)B * D * 4); // Cpad*D
    char* X = (char*)wclsb + (size_t)Cpad * D * 2;
    unsigned short* featb = (unsigned short*)X;                       // B*D (dead after gemm1)
    unsigned short* wcatb = featb + (size_t)B * D;                    // Ncat*D (dead after gemm1)
    unsigned short* pre   = (unsigned short*)X;                       // M*D (overlays featb+wcatb)

    // 1) all f32 -> bf16 converts in one launch
    {
        long n1 = (long)DR * D;
        long n2 = (long)D * D;
        long n3 = (long)B * D;
        long n4s = (long)C * D, n4d = (long)Cpad * D;
        long total = n1 + n2 + n3 + n4d;
        convert_all<<<dim3((unsigned)(total / 1024)), 256, 0, stream>>>(
            W_cov, wcatb, n1,
            W_diag, wcatb + n1, n2,
            features, featb, n3,
            W_cls, wclsb, n4s, n4d);
    }

    // 2) fused: lr_cov (bf16) + diag (softplus f32) in one GEMM over [W_cov; W_diag]
    gemm_bf16<3, false><<<dim3((B / 128) * (Ncat / 128)), 256, 0, stream>>>(
        featb, wcatb, b_cov, b_diag, lrcov, diag, B, Ncat, Ncat, D, DR);

    // 3) pre_logits (bf16)
    sample_kernel<<<dim3(B), 256, 0, stream>>>(
        features, lrcov, diag, nz_lr, nz_diag, pre, S, D);

    // 4) logits = (pre @ W_cls^T + b_cls) / 1.5 — 256x256 8-phase kernel
    gemm2_256<true><<<dim3((M / 256) * (Cpad / 256)), 512, 0, stream>>>(
        pre, wclsb, b_cls, (float*)d_out, M, Cpad, C, D);
}